// Round 1
// 833.725 us; speedup vs baseline: 1.0056x; 1.0056x over previous
//
#include <hip/hip_runtime.h>

// Problem constants: B=2, C=128, H=800, W=640, N=10000, 18 conv outputs (9 neighbors x 2)
constexpr int BB = 2;
constexpr int CC = 128;
constexpr int HH = 800;
constexpr int WW = 640;
constexpr int NN = 10000;
constexpr int OO = 18;
constexpr int NP = BB * NN;      // 20000 points
constexpr size_t HWsz = (size_t)HH * WW;              // 512000 pixels
constexpr int TP = 64;                                 // pixels per transpose tile
constexpr int TILES_PER_B = (int)(HWsz / TP);          // 8000
constexpr size_t WS_TRANS_BYTES = (size_t)BB * HWsz * CC * sizeof(float);  // 524,288,000

// ---- legacy banded-path workspace (fallback #1) ----
constexpr int S2 = NP * 8;
constexpr int BAND_SHIFT = 2;
constexpr int NB = (HH + (1 << BAND_SHIFT) - 1) >> BAND_SHIFT;
constexpr size_t WS_COORDS = 0;
constexpr size_t WS_SGX    = WS_COORDS + sizeof(float) * 2 * S2;
constexpr size_t WS_SGY    = WS_SGX + sizeof(float) * S2;
constexpr size_t WS_SID    = WS_SGY + sizeof(float) * S2;
constexpr size_t WS_HIST   = WS_SID + sizeof(unsigned) * S2;
constexpr size_t WS_CUR    = WS_HIST + sizeof(unsigned) * 256;
constexpr size_t WS_BAND_NEEDED = WS_CUR + sizeof(unsigned) * 256;

__device__ __forceinline__ float to_px_x(float v) {
    float g = (v + 1.0f) * 0.5f * (float)(WW - 1);
    return fminf(fmaxf(g, 0.0f), (float)(WW - 1));
}
__device__ __forceinline__ float to_px_y(float v) {
    float g = (v + 1.0f) * 0.5f * (float)(HH - 1);
    return fminf(fmaxf(g, 0.0f), (float)(HH - 1));
}

// ===================== Fast path: transpose + fused coalesced gather =====================

// kT: (B,C,H,W) -> (B,HW,C). Tile = 64 pixels x 128 channels, LDS-mediated.
// LDS layout [pix][CC+1] (row stride 129 floats): both phases <=2-way bank alias (free).
__global__ void __launch_bounds__(256)
kT(const float* __restrict__ img, float* __restrict__ trans) {
    __shared__ float lds[TP][CC + 1];
    const int tile = blockIdx.x;
    const int b = tile / TILES_PER_B;
    const int pix0 = (tile - b * TILES_PER_B) * TP;
    const int t = threadIdx.x;

    // Read phase: 8 rounds x (16 channels x 64 pixels via float4)
    const int cg   = t & 15;   // pixel group (4 px each)
    const int crow = t >> 4;   // 0..15
    #pragma unroll
    for (int r = 0; r < 8; ++r) {
        const int c = r * 16 + crow;
        const float4 v = *(const float4*)(img + ((size_t)(b * CC + c)) * HWsz + pix0 + 4 * cg);
        lds[4 * cg + 0][c] = v.x;
        lds[4 * cg + 1][c] = v.y;
        lds[4 * cg + 2][c] = v.z;
        lds[4 * cg + 3][c] = v.w;
    }
    __syncthreads();

    // Write phase: 8 rounds x (8 pixels x 32 float4-chunks) = float4 stores, coalesced.
    const int pl = t & 7;        // pixel within group of 8
    const int k  = t >> 3;       // channel chunk 0..31 (4 channels each)
    float* tbase = trans + ((size_t)b * HWsz + pix0) * CC;
    #pragma unroll
    for (int it = 0; it < 8; ++it) {
        const int pix = it * 8 + pl;
        float4 v;
        v.x = lds[pix][4 * k + 0];
        v.y = lds[pix][4 * k + 1];
        v.z = lds[pix][4 * k + 2];
        v.w = lds[pix][4 * k + 3];
        *(float4*)(tbase + (size_t)pix * CC + 4 * k) = v;
    }
}

// Bilinear from NHWC-transposed image; each thread handles 4 contiguous channels (float4 taps).
__device__ __forceinline__ float4 bilin4(const float* __restrict__ tb,
                                         float gx, float gy, int c4) {
    float x0f = floorf(gx);
    float y0f = floorf(gy);
    int x0 = (int)x0f;
    int y0 = (int)y0f;
    int x1 = min(x0 + 1, WW - 1);
    int y1 = min(y0 + 1, HH - 1);
    float wx1 = gx - x0f;
    float wy1 = gy - y0f;
    float wx0 = 1.0f - wx1;
    float wy0 = 1.0f - wy1;
    const float* r0 = tb + ((size_t)y0 * WW) * CC;
    const float* r1 = tb + ((size_t)y1 * WW) * CC;
    const float4 v00 = *(const float4*)(r0 + (size_t)x0 * CC + c4);
    const float4 v01 = *(const float4*)(r0 + (size_t)x1 * CC + c4);
    const float4 v10 = *(const float4*)(r1 + (size_t)x0 * CC + c4);
    const float4 v11 = *(const float4*)(r1 + (size_t)x1 * CC + c4);
    float4 r;
    r.x = (v00.x * wx0 + v01.x * wx1) * wy0 + (v10.x * wx0 + v11.x * wx1) * wy1;
    r.y = (v00.y * wx0 + v01.y * wx1) * wy0 + (v10.y * wx0 + v11.y * wx1) * wy1;
    r.z = (v00.z * wx0 + v01.z * wx1) * wy0 + (v10.z * wx0 + v11.z * wx1) * wy1;
    r.w = (v00.w * wx0 + v01.w * wx1) * wy0 + (v10.w * wx0 + v11.w * wx1) * wy1;
    return r;
}

// kG: 8 points per 256-thread block; 32 lanes per point, 4 channels per lane.
// All taps are 16 B/lane float4 loads (512 B per point per tap, coalesced).
constexpr int PPB = 8;  // points per block
__global__ void __launch_bounds__(256)
kG(const float* __restrict__ trans, const float* __restrict__ verts,
   const float* __restrict__ conv_w, const float* __restrict__ conv_b,
   float* __restrict__ out) {
    const int t    = threadIdx.x;
    const int pt   = t >> 5;        // point slot 0..7
    const int lane = t & 31;
    const int c4   = lane * 4;      // first of this thread's 4 channels
    const int p    = blockIdx.x * PPB + pt;   // NP = 20000 = 2500*8, always in range
    const int b    = p / NN;

    __shared__ float s_feat[PPB][CC + 4];   // +4 pad: row starts spread over banks
    __shared__ float s_delta[PPB][OO];

    // vertex broadcast (same address across the 32 lanes of a point -> L1 broadcast)
    const float vx = verts[(size_t)p * 2 + 0];
    const float vy = verts[(size_t)p * 2 + 1];
    const float* tb = trans + (size_t)b * HWsz * CC;

    // center sample
    const float4 fc = bilin4(tb, to_px_x(vx), to_px_y(vy), c4);
    s_feat[pt][c4 + 0] = fc.x;
    s_feat[pt][c4 + 1] = fc.y;
    s_feat[pt][c4 + 2] = fc.z;
    s_feat[pt][c4 + 3] = fc.w;
    __syncthreads();

    // matvec: 144 parallel dot products (8 points x 18 outputs)
    if (t < PPB * OO) {
        const int pp = t / OO;
        const int o  = t - pp * OO;
        float acc = conv_b[o];
        const float* wrow = conv_w + o * CC;
        #pragma unroll 8
        for (int kk = 0; kk < CC; ++kk) acc += wrow[kk] * s_feat[pp][kk];
        s_delta[pp][o] = acc;
    }
    __syncthreads();

    // 8 neighbor samples, accumulate with center
    float4 acc = fc;
    #pragma unroll
    for (int j = 1; j < 9; ++j) {
        const float nx = vx + s_delta[pt][2 * j + 0];
        const float ny = vy + s_delta[pt][2 * j + 1];
        const float4 v = bilin4(tb, to_px_x(nx), to_px_y(ny), c4);
        acc.x += v.x; acc.y += v.y; acc.z += v.z; acc.w += v.w;
    }
    const float s = 1.0f / 9.0f;
    float4 res;
    res.x = acc.x * s; res.y = acc.y * s; res.z = acc.z * s; res.w = acc.w * s;
    *(float4*)(out + (size_t)p * CC + c4) = res;
}

// ===================== Fallback #1: R2 banded path =====================

__device__ __forceinline__ float bilin_px(const float* __restrict__ base,
                                          float gx, float gy) {
    float x0f = floorf(gx);
    float y0f = floorf(gy);
    int x0 = (int)x0f;
    int y0 = (int)y0f;
    int x1 = min(x0 + 1, WW - 1);
    int y1 = min(y0 + 1, HH - 1);
    float wx1 = gx - x0f;
    float wy1 = gy - y0f;
    float wx0 = 1.0f - wx1;
    float wy0 = 1.0f - wy1;
    const float* r0 = base + (size_t)y0 * WW;
    const float* r1 = base + (size_t)y1 * WW;
    return (r0[x0] * wx0 + r0[x1] * wx1) * wy0 +
           (r1[x0] * wx0 + r1[x1] * wx1) * wy1;
}

__global__ void __launch_bounds__(CC)
k1_center(const float* __restrict__ img, const float* __restrict__ verts,
          const float* __restrict__ conv_w, const float* __restrict__ conv_b,
          float* __restrict__ out, float2* __restrict__ coords,
          unsigned* __restrict__ hist) {
    const int p = blockIdx.x;
    const int b = p / NN;
    const int c = threadIdx.x;
    __shared__ float s_feat[CC];
    __shared__ float s_delta[OO];
    const float vx = verts[(size_t)p * 2 + 0];
    const float vy = verts[(size_t)p * 2 + 1];
    const float* base = img + ((size_t)(b * CC + c)) * HWsz;
    const float fc = bilin_px(base, to_px_x(vx), to_px_y(vy));
    s_feat[c] = fc;
    __syncthreads();
    if (c < OO) {
        float acc = conv_b[c];
        const float* wrow = conv_w + c * CC;
        for (int k = 0; k < CC; ++k) acc += wrow[k] * s_feat[k];
        s_delta[c] = acc;
    }
    __syncthreads();
    out[(size_t)p * CC + c] = fc * (1.0f / 9.0f);
    if (c >= 1 && c < 9) {
        const float ggx = to_px_x(vx + s_delta[2 * c + 0]);
        const float ggy = to_px_y(vy + s_delta[2 * c + 1]);
        coords[p * 8 + (c - 1)] = make_float2(ggx, ggy);
        atomicAdd(&hist[((int)ggy) >> BAND_SHIFT], 1u);
    }
}

__global__ void k2_scan(const unsigned* __restrict__ hist, unsigned* __restrict__ cursor) {
    if (threadIdx.x == 0 && blockIdx.x == 0) {
        unsigned acc = 0;
        for (int i = 0; i < NB; ++i) { cursor[i] = acc; acc += hist[i]; }
    }
}

__global__ void __launch_bounds__(256)
k3_scatter(const float2* __restrict__ coords, unsigned* __restrict__ cursor,
           float* __restrict__ sgx, float* __restrict__ sgy, unsigned* __restrict__ sid) {
    const int i = blockIdx.x * 256 + threadIdx.x;
    if (i < S2) {
        const float2 cd = coords[i];
        const unsigned pos = atomicAdd(&cursor[((int)cd.y) >> BAND_SHIFT], 1u);
        sgx[pos] = cd.x; sgy[pos] = cd.y; sid[pos] = (unsigned)(i >> 3);
    }
}

__global__ void __launch_bounds__(CC)
k4_sample(const float* __restrict__ img, const float* __restrict__ sgx,
          const float* __restrict__ sgy, const unsigned* __restrict__ sid,
          float* __restrict__ out) {
    const int r = blockIdx.x;
    const int c = threadIdx.x;
    const unsigned p = sid[r];
    const int b = (p >= (unsigned)NN) ? 1 : 0;
    const float* base = img + ((size_t)(b * CC + c)) * HWsz;
    const float v = bilin_px(base, sgx[r], sgy[r]);
    atomicAdd(&out[(size_t)p * CC + c], v * (1.0f / 9.0f));
}

// ===================== Fallback #2: monolithic =====================

__global__ void __launch_bounds__(CC)
lns_kernel(const float* __restrict__ img, const float* __restrict__ verts,
           const float* __restrict__ conv_w, const float* __restrict__ conv_b,
           float* __restrict__ out) {
    const int p = blockIdx.x;
    const int b = p / NN;
    const int c = threadIdx.x;
    __shared__ float s_feat[CC];
    __shared__ float s_delta[OO];
    const float vx = verts[(size_t)p * 2 + 0];
    const float vy = verts[(size_t)p * 2 + 1];
    const float* base = img + ((size_t)(b * CC + c)) * HWsz;
    const float fc = bilin_px(base, to_px_x(vx), to_px_y(vy));
    s_feat[c] = fc;
    __syncthreads();
    if (c < OO) {
        float acc = conv_b[c];
        const float* wrow = conv_w + c * CC;
        for (int k = 0; k < CC; ++k) acc += wrow[k] * s_feat[k];
        s_delta[c] = acc;
    }
    __syncthreads();
    float acc = fc;
    for (int j = 1; j < 9; ++j)
        acc += bilin_px(base, to_px_x(vx + s_delta[2 * j]), to_px_y(vy + s_delta[2 * j + 1]));
    out[(size_t)p * CC + c] = acc * (1.0f / 9.0f);
}

extern "C" void kernel_launch(void* const* d_in, const int* in_sizes, int n_in,
                              void* d_out, int out_size, void* d_ws, size_t ws_size,
                              hipStream_t stream) {
    const float* img    = (const float*)d_in[0];
    const float* verts  = (const float*)d_in[1];
    const float* conv_w = (const float*)d_in[2];
    const float* conv_b = (const float*)d_in[3];
    float* out = (float*)d_out;

    if (ws_size >= WS_TRANS_BYTES) {
        float* trans = (float*)d_ws;
        kT<<<dim3(BB * TILES_PER_B), dim3(256), 0, stream>>>(img, trans);
        kG<<<dim3(NP / PPB), dim3(256), 0, stream>>>(trans, verts, conv_w, conv_b, out);
        return;
    }

    if (ws_size >= WS_BAND_NEEDED) {
        char* w = (char*)d_ws;
        float2*   coords = (float2*)(w + WS_COORDS);
        float*    sgx    = (float*)(w + WS_SGX);
        float*    sgy    = (float*)(w + WS_SGY);
        unsigned* sid    = (unsigned*)(w + WS_SID);
        unsigned* hist   = (unsigned*)(w + WS_HIST);
        unsigned* cursor = (unsigned*)(w + WS_CUR);
        hipMemsetAsync(hist, 0, sizeof(unsigned) * 256, stream);
        k1_center<<<dim3(NP), dim3(CC), 0, stream>>>(img, verts, conv_w, conv_b, out, coords, hist);
        k2_scan<<<dim3(1), dim3(64), 0, stream>>>(hist, cursor);
        k3_scatter<<<dim3((S2 + 255) / 256), dim3(256), 0, stream>>>(coords, cursor, sgx, sgy, sid);
        k4_sample<<<dim3(S2), dim3(CC), 0, stream>>>(img, sgx, sgy, sid, out);
        return;
    }

    lns_kernel<<<dim3(NP), dim3(CC), 0, stream>>>(img, verts, conv_w, conv_b, out);
}